// Round 4
// baseline (607.931 us; speedup 1.0000x reference)
//
#include <hip/hip_runtime.h>
#include <hip/hip_bf16.h>

typedef __attribute__((ext_vector_type(8))) short bf16x8;
typedef __attribute__((ext_vector_type(4))) float f32x4;
typedef __attribute__((ext_vector_type(16))) float f32x16;

#define MFMA32(a, b, c) __builtin_amdgcn_mfma_f32_32x32x16_bf16(a, b, c, 0, 0, 0)

__device__ __forceinline__ short f2bf(float f) {
    union { __hip_bfloat16 h; short s; } u;
    u.h = __float2bfloat16(f);
    return u.s;
}

__device__ __forceinline__ bf16x8 cvt8(const float* __restrict__ p) {
    f32x4 a = *reinterpret_cast<const f32x4*>(p);
    f32x4 b = *reinterpret_cast<const f32x4*>(p + 4);
    bf16x8 r;
    r[0] = f2bf(a[0]); r[1] = f2bf(a[1]); r[2] = f2bf(a[2]); r[3] = f2bf(a[3]);
    r[4] = f2bf(b[0]); r[5] = f2bf(b[1]); r[6] = f2bf(b[2]); r[7] = f2bf(b[3]);
    return r;
}

typedef __attribute__((address_space(1))) const unsigned int g_u32;
typedef __attribute__((address_space(3))) unsigned int l_u32;
__device__ __forceinline__ void gld16(const void* g, void* l) {
    __builtin_amdgcn_global_load_lds((g_u32*)(g), (l_u32*)(l), 16, 0, 0);
}

// ---------------------------------------------------------------------------
// Kernel 0: convert Wq|Wk|Wv (fp32, 3x65536) to bf16 into d_out scratch.
// ---------------------------------------------------------------------------
__global__ void wcvt_kernel(const float* __restrict__ Wq, const float* __restrict__ Wk,
                            const float* __restrict__ Wv, short* __restrict__ Wb)
{
    int t = blockIdx.x * 256 + threadIdx.x;
    int idx = t * 8;
    const float* src = idx < 65536 ? Wq + idx
                     : (idx < 131072 ? Wk + (idx - 65536) : Wv + (idx - 131072));
    *reinterpret_cast<bf16x8*>(Wb + idx) = cvt8(src);
}

// ---------------------------------------------------------------------------
// Kernel 1: fused QKV, 32x32x16 MFMA. 4 waves x 32 rows = 128 rows/block,
// 256 blocks. W bf16 read direct from global (L2-hot, 384KB total).
// q,k: direct bf16 stores [S][D]. v: LDS transpose -> [D][S].
// ---------------------------------------------------------------------------
__global__ __launch_bounds__(256, 2) void qkv_kernel(
    const float* __restrict__ x, const short* __restrict__ Wb,
    const float* __restrict__ bq, const float* __restrict__ bk, const float* __restrict__ bv,
    short* __restrict__ qo, short* __restrict__ ko, short* __restrict__ vto)
{
    const int wave = threadIdx.x >> 6, lane = threadIdx.x & 63;
    const int l31 = lane & 31, h = lane >> 5;
    const int row0 = blockIdx.x * 128;
    const int wrow = row0 + wave * 32;

    // A frags: x rows (wrow+l31), d = kc*16 + h*8 .. +7, fp32->bf16 inline
    bf16x8 af[16];
    const float* __restrict__ xr = x + (size_t)(wrow + l31) * 256 + h * 8;
#pragma unroll
    for (int kc = 0; kc < 16; ++kc) af[kc] = cvt8(xr + kc * 16);

    __shared__ short tile[128][264];

    for (int proj = 0; proj < 3; ++proj) {
        const short* __restrict__ W = Wb + proj * 65536;
        const float* __restrict__ bias = proj == 0 ? bq : (proj == 1 ? bk : bv);

        f32x16 acc[8];
#pragma unroll
        for (int df = 0; df < 8; ++df)
#pragma unroll
            for (int e = 0; e < 16; ++e) acc[df][e] = 0.f;

#pragma unroll
        for (int kc = 0; kc < 16; ++kc)
#pragma unroll
            for (int df = 0; df < 8; ++df) {
                bf16x8 bfr = *reinterpret_cast<const bf16x8*>(
                    W + (df * 32 + l31) * 256 + kc * 16 + h * 8);
                acc[df] = MFMA32(af[kc], bfr, acc[df]);
            }

        if (proj < 2) {
            short* __restrict__ dst = proj == 0 ? qo : ko;
#pragma unroll
            for (int df = 0; df < 8; ++df) {
                int col = df * 32 + l31;
                float bv_ = bias[col];
#pragma unroll
                for (int rg = 0; rg < 16; ++rg) {
                    int r = (rg & 3) + 8 * (rg >> 2) + 4 * h;
                    dst[(size_t)(wrow + r) * 256 + col] = f2bf(acc[df][rg] + bv_);
                }
            }
        } else {
#pragma unroll
            for (int df = 0; df < 8; ++df) {
                int col = df * 32 + l31;
                float bv_ = bias[col];
#pragma unroll
                for (int rg = 0; rg < 16; ++rg) {
                    int r = (rg & 3) + 8 * (rg >> 2) + 4 * h;
                    tile[wave * 32 + r][col] = f2bf(acc[df][rg] + bv_);
                }
            }
            __syncthreads();
            int d = threadIdx.x;
            int bb = row0 >> 12, s0 = row0 & 4095;
            short* __restrict__ dst = vto + ((size_t)bb * 256 + d) * 4096 + s0;
#pragma unroll
            for (int i = 0; i < 16; ++i) {
                bf16x8 v;
#pragma unroll
                for (int j = 0; j < 8; ++j) v[j] = tile[i * 8 + j][d];
                *reinterpret_cast<bf16x8*>(dst + i * 8) = v;
            }
        }
    }
}

// ---------------------------------------------------------------------------
// Kernel 2: flash attention + residual. 32x32x16 MFMA, 4 waves x 32 q-rows,
// KVBLK=64. K and V both double-buffered in LDS via global_load_lds (w16),
// LANE-LINEAR slot order (conflict-free b128 reads). One barrier per iter.
// Per-lane partial row-sums (no per-iter sum shuffles); defer-max rescale.
// Grid 256: batch = id&7 (XCD-affine), qtile = id>>3.
// LDS: K 2x32KB + V 2x32KB + P 4x4.6KB = 146 KB -> 1 block/CU.
// ---------------------------------------------------------------------------
__global__ __launch_bounds__(256, 1) void attn_kernel(
    const short* __restrict__ q, const short* __restrict__ k,
    const short* __restrict__ vt, const float* __restrict__ x,
    float* __restrict__ out)
{
    const int id = blockIdx.x;
    const int b = id & 7, qt = id >> 3;
    const int tid = threadIdx.x;
    const int wave = tid >> 6, lane = tid & 63;
    const int l31 = lane & 31, h = lane >> 5;
    const int qrow0 = qt * 128 + wave * 32;

    const short* __restrict__ qb = q  + (size_t)b * 4096 * 256;
    const short* __restrict__ kb = k  + (size_t)b * 4096 * 256;
    const short* __restrict__ vb = vt + (size_t)b * 256 * 4096;

    __shared__ short klds[2][16384];   // slot = nf*1024 + kc*64 + lane (16B each)
    __shared__ short vlds[2][16384];   // slot = df*256 + k2*64 + lane
    __shared__ short plds[4][32][72];  // per-wave P: [row][key], pitch 144B

    // Q A-frags: lane holds Q[qrow0+l31][kc*16 + h*8 .. +7]
    bf16x8 qf[16];
    const short* __restrict__ qr = qb + (size_t)(qrow0 + l31) * 256 + h * 8;
#pragma unroll
    for (int kc = 0; kc < 16; ++kc)
        qf[kc] = *reinterpret_cast<const bf16x8*>(qr + kc * 16);

    f32x16 o[8];
#pragma unroll
    for (int df = 0; df < 8; ++df)
#pragma unroll
        for (int e = 0; e < 16; ++e) o[df][e] = 0.f;

    float m2[16], ls[16];
#pragma unroll
    for (int rg = 0; rg < 16; ++rg) { m2[rg] = -INFINITY; ls[rg] = 0.f; }

    const float cs = 0.0625f * 1.44269504f;   // scale * log2(e)

    // staging: K tile 2048 chunks, V tile 2048 chunks; c = i*256 + tid.
    // LDS dest is linear (c*16B) => per-wave base + lane*16 (gld_lds-legal);
    // the slot->content permutation is applied on the GLOBAL source address.
#define STAGE_K(KV, BUF)                                                       \
    { _Pragma("unroll")                                                        \
      for (int i = 0; i < 8; ++i) {                                            \
          int c = i * 256 + tid;                                               \
          int nf = c >> 10, kc = (c >> 6) & 15, l = c & 63;                    \
          gld16(kb + (size_t)((KV) + nf * 32 + (l & 31)) * 256                 \
                    + kc * 16 + (l >> 5) * 8,                                  \
                &klds[BUF][c * 8]);                                            \
      } }
#define STAGE_V(KV, BUF)                                                       \
    { _Pragma("unroll")                                                        \
      for (int i = 0; i < 8; ++i) {                                            \
          int c = i * 256 + tid;                                               \
          int df = c >> 8, k2 = (c >> 6) & 3, l = c & 63;                      \
          gld16(vb + (size_t)(df * 32 + (l & 31)) * 4096 + (KV)                \
                    + k2 * 16 + (l >> 5) * 8,                                  \
                &vlds[BUF][c * 8]);                                            \
      } }

    STAGE_K(0, 0);
    STAGE_V(0, 0);
    __syncthreads();

    short (*pw)[72] = plds[wave];

    for (int t = 0; t < 64; ++t) {
        const int kv = t * 64, cur = t & 1;
        if (t < 63) { STAGE_K(kv + 64, cur ^ 1); STAGE_V(kv + 64, cur ^ 1); }

        // ---- QK^T: s0v = keys kv..kv+31, s1v = kv+32..kv+63
        f32x16 s0v, s1v;
#pragma unroll
        for (int e = 0; e < 16; ++e) { s0v[e] = 0.f; s1v[e] = 0.f; }
        const short* __restrict__ kbase = klds[cur];
#pragma unroll
        for (int kc = 0; kc < 16; ++kc) {
            bf16x8 k0 = *reinterpret_cast<const bf16x8*>(kbase + (kc * 64 + lane) * 8);
            bf16x8 k1 = *reinterpret_cast<const bf16x8*>(kbase + (1024 + kc * 64 + lane) * 8);
            s0v = MFMA32(qf[kc], k0, s0v);
            s1v = MFMA32(qf[kc], k1, s1v);
        }

        // ---- online softmax (log2 domain); rows: r = (rg&3)+8*(rg>>2)+4*h
        float tt0[16], tt1[16], mxa[16];
#pragma unroll
        for (int rg = 0; rg < 16; ++rg) { tt0[rg] = s0v[rg] * cs; tt1[rg] = s1v[rg] * cs; }
#pragma unroll
        for (int rg = 0; rg < 16; ++rg) {
            float v = fmaxf(tt0[rg], tt1[rg]);
#pragma unroll
            for (int d = 1; d < 32; d <<= 1) v = fmaxf(v, __shfl_xor(v, d));
            mxa[rg] = v;
        }
        bool g = false;
#pragma unroll
        for (int rg = 0; rg < 16; ++rg) g = g || (mxa[rg] > m2[rg]);
        if (__any(g)) {
            float al[16];
#pragma unroll
            for (int rg = 0; rg < 16; ++rg) {
                float mn = fmaxf(m2[rg], mxa[rg]);
                float a = exp2f(m2[rg] - mn);
                m2[rg] = mn;
                ls[rg] *= a;
                al[rg] = a;
            }
#pragma unroll
            for (int df = 0; df < 8; ++df)
#pragma unroll
                for (int rg = 0; rg < 16; ++rg) o[df][rg] *= al[rg];
        }

        // ---- exp, per-lane partial row-sum, P -> per-wave LDS (C->A relayout)
#pragma unroll
        for (int rg = 0; rg < 16; ++rg) {
            float p0 = exp2f(tt0[rg] - m2[rg]);
            float p1 = exp2f(tt1[rg] - m2[rg]);
            ls[rg] += p0 + p1;
            int r = (rg & 3) + 8 * (rg >> 2) + 4 * h;
            pw[r][l31]      = f2bf(p0);
            pw[r][32 + l31] = f2bf(p1);
        }
        bf16x8 pf0 = *reinterpret_cast<const bf16x8*>(&pw[l31][h * 8]);
        bf16x8 pf1 = *reinterpret_cast<const bf16x8*>(&pw[l31][16 + h * 8]);
        bf16x8 pf2 = *reinterpret_cast<const bf16x8*>(&pw[l31][32 + h * 8]);
        bf16x8 pf3 = *reinterpret_cast<const bf16x8*>(&pw[l31][48 + h * 8]);

        // ---- PV: o[df] += P(32x64) . V(64x32), V from lane-linear slots
        const short* __restrict__ vbase = vlds[cur];
#pragma unroll
        for (int df = 0; df < 8; ++df) {
            bf16x8 v0 = *reinterpret_cast<const bf16x8*>(vbase + (df * 256 + lane) * 8);
            bf16x8 v1 = *reinterpret_cast<const bf16x8*>(vbase + (df * 256 + 64 + lane) * 8);
            bf16x8 v2 = *reinterpret_cast<const bf16x8*>(vbase + (df * 256 + 128 + lane) * 8);
            bf16x8 v3 = *reinterpret_cast<const bf16x8*>(vbase + (df * 256 + 192 + lane) * 8);
            o[df] = MFMA32(pf0, v0, o[df]);
            o[df] = MFMA32(pf1, v1, o[df]);
            o[df] = MFMA32(pf2, v2, o[df]);
            o[df] = MFMA32(pf3, v3, o[df]);
        }

        __syncthreads();   // all reads of buf[cur] done; prefetch DMA drained
    }

    // ---- epilogue: reduce row-sums once, normalize, residual, store
    float inv[16];
#pragma unroll
    for (int rg = 0; rg < 16; ++rg) {
        float v = ls[rg];
#pragma unroll
        for (int d = 1; d < 32; d <<= 1) v += __shfl_xor(v, d);
        inv[rg] = 1.0f / v;
    }
#pragma unroll
    for (int df = 0; df < 8; ++df) {
        int col = df * 32 + l31;
#pragma unroll
        for (int rg = 0; rg < 16; ++rg) {
            int r = (rg & 3) + 8 * (rg >> 2) + 4 * h;
            size_t row = (size_t)b * 4096 + qrow0 + r;
            out[row * 256 + col] = o[df][rg] * inv[rg] + x[row * 256 + col];
        }
    }
#undef STAGE_K
#undef STAGE_V
}

// ---------------------------------------------------------------------------
extern "C" void kernel_launch(void* const* d_in, const int* in_sizes, int n_in,
                              void* d_out, int out_size, void* d_ws, size_t ws_size,
                              hipStream_t stream) {
    const float* x  = (const float*)d_in[0];
    const float* Wq = (const float*)d_in[1];
    const float* bq = (const float*)d_in[2];
    const float* Wk = (const float*)d_in[3];
    const float* bk = (const float*)d_in[4];
    const float* Wv = (const float*)d_in[5];
    const float* bv = (const float*)d_in[6];
    float* out = (float*)d_out;

    char* ws = (char*)d_ws;
    short* qb  = (short*)ws;                               // 16 MB bf16 [B*S][D]
    short* kb  = (short*)(ws + (size_t)16 * 1024 * 1024);  // 16 MB bf16 [B*S][D]
    short* vtb = (short*)(ws + (size_t)32 * 1024 * 1024);  // 16 MB bf16 [B][D][S]
    short* Wb  = (short*)d_out;   // 384 KB W scratch; attn overwrites out after

    wcvt_kernel<<<96, 256, 0, stream>>>(Wq, Wk, Wv, Wb);

    qkv_kernel<<<256, 256, 0, stream>>>(x, Wb, bq, bk, bv, qb, kb, vtb);

    attn_kernel<<<256, 256, 0, stream>>>(qb, kb, vtb, x, out);
}